// Round 10
// baseline (330.915 us; speedup 1.0000x reference)
//
#include <hip/hip_runtime.h>
#include <hip/hip_bf16.h>

// Fused pre-LN MHA block: LN -> QKV GEMM -> flash attn (KV-split) -> combine ->
// out-proj + residual. All matmuls bf16 MFMA (16x16x32), fp32 accumulate.
//
// Workspace layout (43 MB used):
//   [ 0MB) h      bf16 [4096,1024]   (dead after QKV)  -> opA bf16 [B,H,T,64] unnorm
//   [ 8MB) WqkvT  bf16 [3072,1024]   (dead after QKV)  -> opB
//   [16MB) lpA f32 [B*H*T], [16.5MB) lpB
//   [17MB) WoutT  bf16 [1024,1024]
//   [19MB) q      bf16 [B,H,T,64]    (dead after attn) -> attno bf16 [4096,1024]
//   [27MB) k      bf16 [B,H,T,64]
//   [35MB) vT     bf16 [B,H,64,T]

#define DINL static __device__ __forceinline__

typedef __attribute__((ext_vector_type(8))) short bf16x8;
typedef __attribute__((ext_vector_type(4))) float f32x4;

DINL float fast_exp2(float x) { return __builtin_amdgcn_exp2f(x); }

DINL unsigned short f2bf(float f) {
  __hip_bfloat16 h = __float2bfloat16(f);
  unsigned short u;
  __builtin_memcpy(&u, &h, 2);
  return u;
}

// cheap round-half-up f32->bf16 (abs err <= 1 ulp; fine at 0.1 threshold)
DINL unsigned int bfbits(float f) {
  unsigned int u;
  __builtin_memcpy(&u, &f, 4);
  return (u + 0x8000u) >> 16;
}

DINL float bf2f(unsigned short u) {
  unsigned int x = ((unsigned int)u) << 16;
  float f;
  __builtin_memcpy(&f, &x, 4);
  return f;
}

DINL void gload_lds16(const void* g, void* l) {
  __builtin_amdgcn_global_load_lds((__attribute__((address_space(1))) void*)g,
                                   (__attribute__((address_space(3))) void*)l,
                                   16, 0, 0);
}

// ---------------- LayerNorm (fp32 -> bf16) ----------------
__global__ __launch_bounds__(256)
void ln_kernel(const float* __restrict__ x, const float* __restrict__ gamma,
               const float* __restrict__ beta, unsigned short* __restrict__ h) {
  __shared__ float red[8];
  int row = blockIdx.x;
  int t = threadIdx.x;
  float4 v = reinterpret_cast<const float4*>(x + (size_t)row * 1024)[t];
  float s  = v.x + v.y + v.z + v.w;
  float sq = v.x*v.x + v.y*v.y + v.z*v.z + v.w*v.w;
#pragma unroll
  for (int off = 1; off < 64; off <<= 1) {
    s  += __shfl_xor(s, off);
    sq += __shfl_xor(sq, off);
  }
  int wid = t >> 6;
  if ((t & 63) == 0) { red[wid] = s; red[4 + wid] = sq; }
  __syncthreads();
  s  = red[0] + red[1] + red[2] + red[3];
  sq = red[4] + red[5] + red[6] + red[7];
  float mu   = s * (1.0f / 1024.0f);
  float var  = sq * (1.0f / 1024.0f) - mu * mu;
  float rstd = rsqrtf(var + 1e-5f);
  float4 g = reinterpret_cast<const float4*>(gamma)[t];
  float4 b = reinterpret_cast<const float4*>(beta)[t];
  ushort4 o;
  o.x = f2bf((v.x - mu) * rstd * g.x + b.x);
  o.y = f2bf((v.y - mu) * rstd * g.y + b.y);
  o.z = f2bf((v.z - mu) * rstd * g.z + b.z);
  o.w = f2bf((v.w - mu) * rstd * g.w + b.w);
  reinterpret_cast<ushort4*>(h + (size_t)row * 1024)[t] = o;
}

// ---------------- Transpose + cast: src fp32 [R,C] -> dst bf16 [C,R] ----------------
__global__ __launch_bounds__(256)
void transpose_cast_kernel(const float* __restrict__ src, unsigned short* __restrict__ dst,
                           int R, int C) {
  __shared__ float tile[32][33];
  int tx = threadIdx.x & 31, ty = threadIdx.x >> 5;
  int c0 = blockIdx.x * 32, r0 = blockIdx.y * 32;
#pragma unroll
  for (int i = 0; i < 4; i++)
    tile[ty + i * 8][tx] = src[(size_t)(r0 + ty + i * 8) * C + c0 + tx];
  __syncthreads();
#pragma unroll
  for (int i = 0; i < 4; i++) {
    int r = ty + i * 8;
    dst[(size_t)(c0 + r) * R + r0 + tx] = f2bf(tile[tx][r]);
  }
}

// ---------------- GEMM: C[M,N] = A[M,K] * Bt[N,K]^T (+epilogue) ----------------
template <int BM, int MODE>
__global__ __launch_bounds__(256)
void gemm128(const unsigned short* __restrict__ A,
             const unsigned short* __restrict__ Bt,
             int K,
             const float* __restrict__ bias,
             unsigned short* __restrict__ qdst, unsigned short* __restrict__ kdst,
             unsigned short* __restrict__ vTdst,
             const float* __restrict__ xres, float* __restrict__ out) {
  static_assert(BM == 128 || BM == 64, "");
  constexpr int MR = BM / 32;
  __shared__ unsigned short As[BM * 64];
  __shared__ unsigned short Bs[8192];
  int tid = threadIdx.x, wid = tid >> 6, lane = tid & 63;
  int l15 = lane & 15, l4 = lane >> 4;
  int brow = blockIdx.y * BM, bcol = blockIdx.x * 128;
  int wr = wid >> 1, wc = wid & 1;
  f32x4 acc[MR][4] = {};

  for (int kt = 0; kt < K; kt += 64) {
    __syncthreads();
#pragma unroll
    for (int r = 0; r < MR; r++) {
      int c  = wid * (BM * 2) + r * 64;
      int cl = c + lane;
      int kb = cl / BM, row = cl % BM;
      gload_lds16(A + (size_t)(brow + row) * K + kt + kb * 8, As + c * 8);
    }
#pragma unroll
    for (int r = 0; r < 4; r++) {
      int c  = wid * 256 + r * 64;
      int cl = c + lane;
      int kb = cl >> 7, row = cl & 127;
      gload_lds16(Bt + (size_t)(bcol + row) * K + kt + kb * 8, Bs + c * 8);
    }
    __syncthreads();
#pragma unroll
    for (int ks = 0; ks < 2; ks++) {
      int kb = ks * 4 + l4;
      bf16x8 af[MR], bfr[4];
#pragma unroll
      for (int m = 0; m < MR; m++)
        af[m] = *reinterpret_cast<const bf16x8*>(As + (kb * BM + wr * (BM / 2) + m * 16 + l15) * 8);
#pragma unroll
      for (int n = 0; n < 4; n++)
        bfr[n] = *reinterpret_cast<const bf16x8*>(Bs + (kb * 128 + wc * 64 + n * 16 + l15) * 8);
#pragma unroll
      for (int m = 0; m < MR; m++)
#pragma unroll
        for (int n = 0; n < 4; n++)
          acc[m][n] = __builtin_amdgcn_mfma_f32_16x16x32_bf16(af[m], bfr[n], acc[m][n], 0, 0, 0);
    }
  }

  if (MODE == 0) {
    int sec = bcol >> 10;
    int secbase = sec << 10;
#pragma unroll
    for (int m = 0; m < MR; m++) {
      int row0 = brow + wr * (BM / 2) + m * 16 + l4 * 4;
      int b = row0 >> 11, t0 = row0 & 2047;
#pragma unroll
      for (int n = 0; n < 4; n++) {
        int col = (bcol & 1023) + wc * 64 + n * 16 + l15;
        float bv = bias[secbase + col];
        int hh = col >> 6, d = col & 63;
        if (sec == 2) {
          ushort4 pk;
          pk.x = f2bf(acc[m][n][0] + bv);
          pk.y = f2bf(acc[m][n][1] + bv);
          pk.z = f2bf(acc[m][n][2] + bv);
          pk.w = f2bf(acc[m][n][3] + bv);
          *reinterpret_cast<ushort4*>(vTdst + ((size_t)(b * 16 + hh) * 64 + d) * 2048 + t0) = pk;
        } else {
          unsigned short* dst = (sec == 0) ? qdst : kdst;
          float sc = (sec == 0) ? 0.125f * 1.44269504088896f : 1.0f;
#pragma unroll
          for (int j = 0; j < 4; j++)
            dst[((size_t)(b * 16 + hh) * 2048 + t0 + j) * 64 + d] = f2bf((acc[m][n][j] + bv) * sc);
        }
      }
    }
  } else {
#pragma unroll
    for (int m = 0; m < MR; m++) {
      int row0 = brow + wr * (BM / 2) + m * 16 + l4 * 4;
#pragma unroll
      for (int n = 0; n < 4; n++) {
        int col = bcol + wc * 64 + n * 16 + l15;
        float bv = bias[col];
#pragma unroll
        for (int j = 0; j < 4; j++) {
          size_t idx = (size_t)(row0 + j) * 1024 + col;
          out[idx] = acc[m][n][j] + bv + xres[idx];
        }
      }
    }
  }
}

// ---------------- Flash attention (KV-split, static-exp, single-Ps reorder) -------
// Grid 1024 = {head(32) x qblk(16) x split(2)}, XCD-chunked so a head's 32 blocks
// share one XCD L2. Each block: 128 q-rows, 1024 keys (its split half), 8 rounds
// of 128 keys. No-max softmax (p = 2^s, associative) => split halves combine as
// O=(Oa+Ob)/(la+lb) in a separate pass. Round order with SINGLE Ps buffer:
// {QK0 SM0 | QK1 | PV0 | SM1 | PV1}: SM0->PV0 covered by QK1; SM1 overwrites Ps
// AFTER PV0's reads (per-wave DS pipe is in-order). V1 loaded after PV0 (covered
// by SM1) to cap VGPR. LDS 48KB (Ks dbuf 32 + Ps 16) -> 3 blocks/CU, 12 waves/CU.
__global__ __launch_bounds__(256, 3)
void attn_kernel(const unsigned short* __restrict__ q,
                 const unsigned short* __restrict__ kk,
                 const unsigned short* __restrict__ vT,
                 unsigned short* __restrict__ opA, unsigned short* __restrict__ opB,
                 float* __restrict__ lpA, float* __restrict__ lpB) {
  const int T = 2048;
  __shared__ unsigned short Ks[2][8192];   // 32 KB: 128 keys x 8 d-chunks (^key&7)
  __shared__ unsigned short Ps[4][2048];   // 16 KB: per-wave [q32][k64 ^ (q&7)<<3]
  int tid = threadIdx.x, wid = tid >> 6, lane = tid & 63;
  int l15 = lane & 15, l4 = lane >> 4;
  int swz = (l15 & 7) << 3;

  // XCD-chunked bijective remap over {bh, qblk, split}
  int lin = blockIdx.x;                    // 0..1023
  int rl  = (lin & 7) * 128 + (lin >> 3);
  int bh = rl >> 5, rem = rl & 31;
  int bx = rem >> 1, sp = rem & 1;
  int q0 = bx * 128 + wid * 32;
  int kvbase = sp << 10;                   // 0 or 1024

  unsigned short* op = sp ? opB : opA;
  float* lp = sp ? lpB : lpA;
  const unsigned short* qh = q  + (size_t)bh * T * 64;
  const unsigned short* kh = kk + (size_t)bh * T * 64;
  const unsigned short* vh = vT + (size_t)bh * 64 * T;

  bf16x8 qf[2][2];
#pragma unroll
  for (int m = 0; m < 2; m++)
#pragma unroll
    for (int ks = 0; ks < 2; ks++)
      qf[m][ks] = *reinterpret_cast<const bf16x8*>(
          qh + (size_t)(q0 + m * 16 + l15) * 64 + ks * 32 + l4 * 8);

  f32x4 accO[2][4] = {};
  float lst[2] = {0.0f, 0.0f};

#define STAGE128(buf, kv0)                                                     \
  {                                                                            \
    _Pragma("unroll") for (int r = 0; r < 4; r++) {                            \
      int c  = (wid * 4 + r) * 64;                                             \
      int cl = c + lane;                                                       \
      int key = cl >> 3;                                                       \
      int kb  = (cl & 7) ^ (key & 7);                                          \
      gload_lds16(kh + (size_t)((kv0) + key) * 64 + kb * 8, &Ks[buf][c * 8]);  \
    }                                                                          \
  }

  // QK for one 64-key sub-tile into sdst
#define QK(sub, sdst)                                                          \
  {                                                                            \
    __builtin_amdgcn_s_setprio(1);                                             \
    _Pragma("unroll") for (int ks = 0; ks < 2; ks++) {                         \
      _Pragma("unroll") for (int n = 0; n < 4; n++) {                          \
        int kkey = (sub) * 64 + n * 16 + l15;                                  \
        int slot = kkey * 8 + ((ks * 4 + l4) ^ (kkey & 7));                    \
        bf16x8 kf = *reinterpret_cast<const bf16x8*>(&Ks[cur][slot * 8]);      \
        _Pragma("unroll") for (int m = 0; m < 2; m++)                          \
          sdst[m][n] = __builtin_amdgcn_mfma_f32_16x16x32_bf16(                \
              kf, qf[m][ks], sdst[m][n], 0, 0, 0);                             \
      }                                                                        \
    }                                                                          \
    __builtin_amdgcn_s_setprio(0);                                             \
  }

  // p = 2^s, pack to Ps, accumulate per-lane l
#define SM(ssrc)                                                               \
  {                                                                            \
    _Pragma("unroll") for (int m = 0; m < 2; m++) {                            \
      float sum = 0.0f;                                                        \
      _Pragma("unroll") for (int n = 0; n < 4; n++) {                          \
        _Pragma("unroll") for (int j = 0; j < 4; j++) {                        \
          float p = fast_exp2(ssrc[m][n][j]);                                  \
          ssrc[m][n][j] = p;                                                   \
          sum += p;                                                            \
        }                                                                      \
        unsigned int u0 = bfbits(ssrc[m][n][0]) | (bfbits(ssrc[m][n][1]) << 16); \
        unsigned int u1 = bfbits(ssrc[m][n][2]) | (bfbits(ssrc[m][n][3]) << 16); \
        *reinterpret_cast<uint2*>(                                             \
            &Ps[wid][(m * 16 + l15) * 64 + ((n * 16 + l4 * 4) ^ swz)]) =       \
            make_uint2(u0, u1);                                                \
      }                                                                        \
      lst[m] += sum;                                                           \
    }                                                                          \
  }

#define PV(vf)                                                                 \
  {                                                                            \
    __builtin_amdgcn_s_setprio(1);                                             \
    _Pragma("unroll") for (int ks = 0; ks < 2; ks++) {                         \
      _Pragma("unroll") for (int m = 0; m < 2; m++) {                          \
        bf16x8 pf = *reinterpret_cast<const bf16x8*>(                          \
            &Ps[wid][(m * 16 + l15) * 64 + ((ks * 32 + l4 * 8) ^ swz)]);       \
        _Pragma("unroll") for (int n = 0; n < 4; n++)                          \
          accO[m][n] = __builtin_amdgcn_mfma_f32_16x16x32_bf16(                \
              vf[ks][n], pf, accO[m][n], 0, 0, 0);                             \
      }                                                                        \
    }                                                                          \
    __builtin_amdgcn_s_setprio(0);                                             \
  }

#define LOADV(vf, kvs)                                                         \
  {                                                                            \
    _Pragma("unroll") for (int ks = 0; ks < 2; ks++)                           \
      _Pragma("unroll") for (int n = 0; n < 4; n++)                            \
        vf[ks][n] = *reinterpret_cast<const bf16x8*>(                          \
            vh + (size_t)(n * 16 + l15) * T + (kvs) + ks * 32 + l4 * 8);       \
  }

  STAGE128(0, kvbase);
  __syncthreads();
  int cur = 0;

  for (int r8 = 0; r8 < 8; r8++) {
    int kv0 = kvbase + r8 * 128;
    bf16x8 vf0[2][4];
    LOADV(vf0, kv0);                        // used after QK0+SM0+QK1 (~700cyc)
    if (r8 + 1 < 8) STAGE128(cur ^ 1, kv0 + 128);
    f32x4 s0[2][4] = {};
    QK(0, s0);
    SM(s0);                                 // -> Ps
    f32x4 s1[2][4] = {};
    QK(1, s1);                              // covers SM0 write -> PV0 read
    PV(vf0);                                // reads Ps (sub0)
    bf16x8 vf1[2][4];
    LOADV(vf1, kv0 + 64);                   // covered by SM1
    SM(s1);                                 // overwrites Ps AFTER PV0's reads (in-order DS)
    PV(vf1);
    __syncthreads();
    cur ^= 1;
  }
#undef QK
#undef SM
#undef PV
#undef LOADV
#undef STAGE128

  int b = bh >> 4, hh = bh & 15;
#pragma unroll
  for (int m = 0; m < 2; m++) {
    float l = lst[m];
    l += __shfl_xor(l, 16);
    l += __shfl_xor(l, 32);
    int row = q0 + m * 16 + l15;
    if (l4 == 0) lp[(size_t)bh * 2048 + row] = l;
#pragma unroll
    for (int n = 0; n < 4; n++) {
      ushort4 pk;                           // unnormalized partial O, bf16
      pk.x = (unsigned short)bfbits(accO[m][n][0]);
      pk.y = (unsigned short)bfbits(accO[m][n][1]);
      pk.z = (unsigned short)bfbits(accO[m][n][2]);
      pk.w = (unsigned short)bfbits(accO[m][n][3]);
      *reinterpret_cast<ushort4*>(
          &op[(size_t)(b * 2048 + row) * 1024 + hh * 64 + n * 16 + l4 * 4]) = pk;
    }
  }
}

// ---------------- Combine: attno = (Oa + Ob) / (la + lb) ----------------
__global__ __launch_bounds__(256)
void attn_combine(const unsigned short* __restrict__ opA,
                  const unsigned short* __restrict__ opB,
                  const float* __restrict__ lpA, const float* __restrict__ lpB,
                  unsigned short* __restrict__ attno) {
  int i0 = (blockIdx.x * 256 + threadIdx.x) * 8;   // 8 consecutive d within one head
  int r = i0 >> 10, c = i0 & 1023;
  int lidx = ((r >> 11) * 16 + (c >> 6)) * 2048 + (r & 2047);
  float inv = 1.0f / (lpA[lidx] + lpB[lidx]);
  bf16x8 a = *reinterpret_cast<const bf16x8*>(opA + i0);
  bf16x8 bb = *reinterpret_cast<const bf16x8*>(opB + i0);
  bf16x8 o;
#pragma unroll
  for (int k = 0; k < 8; k++)
    o[k] = (short)(unsigned short)bfbits(
        (bf2f((unsigned short)a[k]) + bf2f((unsigned short)bb[k])) * inv);
  *reinterpret_cast<bf16x8*>(attno + i0) = o;
}

extern "C" void kernel_launch(void* const* d_in, const int* in_sizes, int n_in,
                              void* d_out, int out_size, void* d_ws, size_t ws_size,
                              hipStream_t stream) {
  const float* x     = (const float*)d_in[0];
  const float* W_qkv = (const float*)d_in[1];
  const float* b_qkv = (const float*)d_in[2];
  const float* W_out = (const float*)d_in[3];
  const float* b_out = (const float*)d_in[4];
  const float* gamma = (const float*)d_in[5];
  const float* beta  = (const float*)d_in[6];
  float* out = (float*)d_out;

  char* ws = (char*)d_ws;
  const size_t MB = 1024 * 1024;
  unsigned short* h     = (unsigned short*)(ws);                 // [0,8) dead after QKV
  unsigned short* WqkvT = (unsigned short*)(ws + 8 * MB);        // [8,14) dead after QKV
  unsigned short* opA   = (unsigned short*)(ws);                 // [0,8)
  unsigned short* opB   = (unsigned short*)(ws + 8 * MB);        // [8,16)
  float*          lpA   = (float*)(ws + 16 * MB);                // 512 KB
  float*          lpB   = (float*)(ws + 16 * MB + 512 * 1024);   // 512 KB
  unsigned short* WoutT = (unsigned short*)(ws + 17 * MB);       // [17,19)
  unsigned short* qb    = (unsigned short*)(ws + 19 * MB);       // [19,27) dead after attn
  unsigned short* attno = (unsigned short*)(ws + 19 * MB);       // combine output
  unsigned short* kb    = (unsigned short*)(ws + 27 * MB);       // [27,35)
  unsigned short* vTb   = (unsigned short*)(ws + 35 * MB);       // [35,43)

  ln_kernel<<<4096, 256, 0, stream>>>(x, gamma, beta, h);
  transpose_cast_kernel<<<dim3(96, 32), 256, 0, stream>>>(W_qkv, WqkvT, 1024, 3072);
  transpose_cast_kernel<<<dim3(32, 32), 256, 0, stream>>>(W_out, WoutT, 1024, 1024);
  gemm128<128, 0><<<dim3(24, 32), 256, 0, stream>>>(h, WqkvT, 1024, b_qkv, qb, kb, vTb, nullptr, nullptr);
  attn_kernel<<<1024, 256, 0, stream>>>(qb, kb, vTb, opA, opB, lpA, lpB);
  attn_combine<<<2048, 256, 0, stream>>>(opA, opB, lpA, lpB, attno);
  gemm128<64, 1><<<dim3(8, 64), 256, 0, stream>>>(attno, WoutT, 1024, b_out, nullptr, nullptr, nullptr, x, out);
}

// Round 11
// 181.022 us; speedup vs baseline: 1.8280x; 1.8280x over previous
//
#include <hip/hip_runtime.h>
#include <hip/hip_bf16.h>

// Fused pre-LN MHA block: LN -> QKV GEMM -> flash attn (KV-split) -> combine ->
// out-proj + residual. All matmuls bf16 MFMA (16x16x32), fp32 accumulate.
//
// Workspace layout (43 MB used):
//   [ 0MB) h      bf16 [4096,1024]   (dead after QKV)  -> opA bf16 [B,H,T,64] unnorm
//   [ 8MB) WqkvT  bf16 [3072,1024]   (dead after QKV)  -> opB
//   [16MB) lpA f32 [B*H*T], [16.5MB) lpB
//   [17MB) WoutT  bf16 [1024,1024]
//   [19MB) q      bf16 [B,H,T,64]    (dead after attn) -> attno bf16 [4096,1024]
//   [27MB) k      bf16 [B,H,T,64]
//   [35MB) vT     bf16 [B,H,64,T]

#define DINL static __device__ __forceinline__

typedef __attribute__((ext_vector_type(8))) short bf16x8;
typedef __attribute__((ext_vector_type(4))) float f32x4;

DINL float fast_exp2(float x) { return __builtin_amdgcn_exp2f(x); }

DINL unsigned short f2bf(float f) {
  __hip_bfloat16 h = __float2bfloat16(f);
  unsigned short u;
  __builtin_memcpy(&u, &h, 2);
  return u;
}

// cheap round-half-up f32->bf16 (abs err <= 1 ulp; fine at 0.1 threshold)
DINL unsigned int bfbits(float f) {
  unsigned int u;
  __builtin_memcpy(&u, &f, 4);
  return (u + 0x8000u) >> 16;
}

DINL float bf2f(unsigned short u) {
  unsigned int x = ((unsigned int)u) << 16;
  float f;
  __builtin_memcpy(&f, &x, 4);
  return f;
}

DINL void gload_lds16(const void* g, void* l) {
  __builtin_amdgcn_global_load_lds((__attribute__((address_space(1))) void*)g,
                                   (__attribute__((address_space(3))) void*)l,
                                   16, 0, 0);
}

// ---------------- LayerNorm (fp32 -> bf16) ----------------
__global__ __launch_bounds__(256)
void ln_kernel(const float* __restrict__ x, const float* __restrict__ gamma,
               const float* __restrict__ beta, unsigned short* __restrict__ h) {
  __shared__ float red[8];
  int row = blockIdx.x;
  int t = threadIdx.x;
  float4 v = reinterpret_cast<const float4*>(x + (size_t)row * 1024)[t];
  float s  = v.x + v.y + v.z + v.w;
  float sq = v.x*v.x + v.y*v.y + v.z*v.z + v.w*v.w;
#pragma unroll
  for (int off = 1; off < 64; off <<= 1) {
    s  += __shfl_xor(s, off);
    sq += __shfl_xor(sq, off);
  }
  int wid = t >> 6;
  if ((t & 63) == 0) { red[wid] = s; red[4 + wid] = sq; }
  __syncthreads();
  s  = red[0] + red[1] + red[2] + red[3];
  sq = red[4] + red[5] + red[6] + red[7];
  float mu   = s * (1.0f / 1024.0f);
  float var  = sq * (1.0f / 1024.0f) - mu * mu;
  float rstd = rsqrtf(var + 1e-5f);
  float4 g = reinterpret_cast<const float4*>(gamma)[t];
  float4 b = reinterpret_cast<const float4*>(beta)[t];
  ushort4 o;
  o.x = f2bf((v.x - mu) * rstd * g.x + b.x);
  o.y = f2bf((v.y - mu) * rstd * g.y + b.y);
  o.z = f2bf((v.z - mu) * rstd * g.z + b.z);
  o.w = f2bf((v.w - mu) * rstd * g.w + b.w);
  reinterpret_cast<ushort4*>(h + (size_t)row * 1024)[t] = o;
}

// ---------------- Transpose + cast: src fp32 [R,C] -> dst bf16 [C,R] ----------------
__global__ __launch_bounds__(256)
void transpose_cast_kernel(const float* __restrict__ src, unsigned short* __restrict__ dst,
                           int R, int C) {
  __shared__ float tile[32][33];
  int tx = threadIdx.x & 31, ty = threadIdx.x >> 5;
  int c0 = blockIdx.x * 32, r0 = blockIdx.y * 32;
#pragma unroll
  for (int i = 0; i < 4; i++)
    tile[ty + i * 8][tx] = src[(size_t)(r0 + ty + i * 8) * C + c0 + tx];
  __syncthreads();
#pragma unroll
  for (int i = 0; i < 4; i++) {
    int r = ty + i * 8;
    dst[(size_t)(c0 + r) * R + r0 + tx] = f2bf(tile[tx][r]);
  }
}

// ---------------- GEMM: C[M,N] = A[M,K] * Bt[N,K]^T (+epilogue) ----------------
template <int BM, int MODE>
__global__ __launch_bounds__(256)
void gemm128(const unsigned short* __restrict__ A,
             const unsigned short* __restrict__ Bt,
             int K,
             const float* __restrict__ bias,
             unsigned short* __restrict__ qdst, unsigned short* __restrict__ kdst,
             unsigned short* __restrict__ vTdst,
             const float* __restrict__ xres, float* __restrict__ out) {
  static_assert(BM == 128 || BM == 64, "");
  constexpr int MR = BM / 32;
  __shared__ unsigned short As[BM * 64];
  __shared__ unsigned short Bs[8192];
  int tid = threadIdx.x, wid = tid >> 6, lane = tid & 63;
  int l15 = lane & 15, l4 = lane >> 4;
  int brow = blockIdx.y * BM, bcol = blockIdx.x * 128;
  int wr = wid >> 1, wc = wid & 1;
  f32x4 acc[MR][4] = {};

  for (int kt = 0; kt < K; kt += 64) {
    __syncthreads();
#pragma unroll
    for (int r = 0; r < MR; r++) {
      int c  = wid * (BM * 2) + r * 64;
      int cl = c + lane;
      int kb = cl / BM, row = cl % BM;
      gload_lds16(A + (size_t)(brow + row) * K + kt + kb * 8, As + c * 8);
    }
#pragma unroll
    for (int r = 0; r < 4; r++) {
      int c  = wid * 256 + r * 64;
      int cl = c + lane;
      int kb = cl >> 7, row = cl & 127;
      gload_lds16(Bt + (size_t)(bcol + row) * K + kt + kb * 8, Bs + c * 8);
    }
    __syncthreads();
#pragma unroll
    for (int ks = 0; ks < 2; ks++) {
      int kb = ks * 4 + l4;
      bf16x8 af[MR], bfr[4];
#pragma unroll
      for (int m = 0; m < MR; m++)
        af[m] = *reinterpret_cast<const bf16x8*>(As + (kb * BM + wr * (BM / 2) + m * 16 + l15) * 8);
#pragma unroll
      for (int n = 0; n < 4; n++)
        bfr[n] = *reinterpret_cast<const bf16x8*>(Bs + (kb * 128 + wc * 64 + n * 16 + l15) * 8);
#pragma unroll
      for (int m = 0; m < MR; m++)
#pragma unroll
        for (int n = 0; n < 4; n++)
          acc[m][n] = __builtin_amdgcn_mfma_f32_16x16x32_bf16(af[m], bfr[n], acc[m][n], 0, 0, 0);
    }
  }

  if (MODE == 0) {
    int sec = bcol >> 10;
    int secbase = sec << 10;
#pragma unroll
    for (int m = 0; m < MR; m++) {
      int row0 = brow + wr * (BM / 2) + m * 16 + l4 * 4;
      int b = row0 >> 11, t0 = row0 & 2047;
#pragma unroll
      for (int n = 0; n < 4; n++) {
        int col = (bcol & 1023) + wc * 64 + n * 16 + l15;
        float bv = bias[secbase + col];
        int hh = col >> 6, d = col & 63;
        if (sec == 2) {
          ushort4 pk;
          pk.x = f2bf(acc[m][n][0] + bv);
          pk.y = f2bf(acc[m][n][1] + bv);
          pk.z = f2bf(acc[m][n][2] + bv);
          pk.w = f2bf(acc[m][n][3] + bv);
          *reinterpret_cast<ushort4*>(vTdst + ((size_t)(b * 16 + hh) * 64 + d) * 2048 + t0) = pk;
        } else {
          unsigned short* dst = (sec == 0) ? qdst : kdst;
          float sc = (sec == 0) ? 0.125f * 1.44269504088896f : 1.0f;
#pragma unroll
          for (int j = 0; j < 4; j++)
            dst[((size_t)(b * 16 + hh) * 2048 + t0 + j) * 64 + d] = f2bf((acc[m][n][j] + bv) * sc);
        }
      }
    }
  } else {
#pragma unroll
    for (int m = 0; m < MR; m++) {
      int row0 = brow + wr * (BM / 2) + m * 16 + l4 * 4;
#pragma unroll
      for (int n = 0; n < 4; n++) {
        int col = bcol + wc * 64 + n * 16 + l15;
        float bv = bias[col];
#pragma unroll
        for (int j = 0; j < 4; j++) {
          size_t idx = (size_t)(row0 + j) * 1024 + col;
          out[idx] = acc[m][n][j] + bv + xres[idx];
        }
      }
    }
  }
}

// ---------------- Flash attention (KV-split, static-exp, sequential subtiles) -----
// Grid 1024 = {head(32) x qblk(16) x split(2)}, XCD-chunked. Each block: 128 q-rows,
// 1024 keys, 8 rounds of 128 keys. No-max softmax (p = 2^s, associative) =>
// split halves combine as O=(Oa+Ob)/(la+lb) in a separate pass.
// R8-proven sequential order, SINGLE s tile live at a time (R10's dual-s spilled):
// {QK0 SM0 PV0 | QK1 SM1 PV1}; Ps single-buffered (wave-private, per-wave DS pipe
// is in-order so SM1's overwrite lands after PV0's reads). vf1 issued before PV0
// (flies under PV0+QK1+SM1). LDS 48KB (Ks dbuf 32 + Ps 16) -> 3 blocks/CU.
__global__ __launch_bounds__(256, 2)
void attn_kernel(const unsigned short* __restrict__ q,
                 const unsigned short* __restrict__ kk,
                 const unsigned short* __restrict__ vT,
                 unsigned short* __restrict__ opA, unsigned short* __restrict__ opB,
                 float* __restrict__ lpA, float* __restrict__ lpB) {
  const int T = 2048;
  __shared__ unsigned short Ks[2][8192];   // 32 KB: 128 keys x 8 d-chunks (^key&7)
  __shared__ unsigned short Ps[4][2048];   // 16 KB: per-wave [q32][k64 ^ (q&7)<<3]
  int tid = threadIdx.x, wid = tid >> 6, lane = tid & 63;
  int l15 = lane & 15, l4 = lane >> 4;
  int swz = (l15 & 7) << 3;

  // XCD-chunked bijective remap over {bh, qblk, split}
  int lin = blockIdx.x;                    // 0..1023
  int rl  = (lin & 7) * 128 + (lin >> 3);
  int bh = rl >> 5, rem = rl & 31;
  int bx = rem >> 1, sp = rem & 1;
  int q0 = bx * 128 + wid * 32;
  int kvbase = sp << 10;                   // 0 or 1024

  unsigned short* op = sp ? opB : opA;
  float* lp = sp ? lpB : lpA;
  const unsigned short* qh = q  + (size_t)bh * T * 64;
  const unsigned short* kh = kk + (size_t)bh * T * 64;
  const unsigned short* vh = vT + (size_t)bh * 64 * T;

  bf16x8 qf[2][2];
#pragma unroll
  for (int m = 0; m < 2; m++)
#pragma unroll
    for (int ks = 0; ks < 2; ks++)
      qf[m][ks] = *reinterpret_cast<const bf16x8*>(
          qh + (size_t)(q0 + m * 16 + l15) * 64 + ks * 32 + l4 * 8);

  f32x4 accO[2][4] = {};
  float lst[2] = {0.0f, 0.0f};

#define STAGE128(buf, kv0)                                                     \
  {                                                                            \
    _Pragma("unroll") for (int r = 0; r < 4; r++) {                            \
      int c  = (wid * 4 + r) * 64;                                             \
      int cl = c + lane;                                                       \
      int key = cl >> 3;                                                       \
      int kb  = (cl & 7) ^ (key & 7);                                          \
      gload_lds16(kh + (size_t)((kv0) + key) * 64 + kb * 8, &Ks[buf][c * 8]);  \
    }                                                                          \
  }

  // one 64-key sub-tile: QK -> p=2^s -> Ps -> PV   (single s, single Ps)
#define SUBTILE(sub, vf)                                                       \
  {                                                                            \
    f32x4 s[2][4] = {};                                                        \
    __builtin_amdgcn_s_setprio(1);                                             \
    _Pragma("unroll") for (int ks = 0; ks < 2; ks++) {                         \
      _Pragma("unroll") for (int n = 0; n < 4; n++) {                          \
        int kkey = (sub) * 64 + n * 16 + l15;                                  \
        int slot = kkey * 8 + ((ks * 4 + l4) ^ (kkey & 7));                    \
        bf16x8 kf = *reinterpret_cast<const bf16x8*>(&Ks[cur][slot * 8]);      \
        _Pragma("unroll") for (int m = 0; m < 2; m++)                          \
          s[m][n] = __builtin_amdgcn_mfma_f32_16x16x32_bf16(kf, qf[m][ks],     \
                                                            s[m][n], 0, 0, 0); \
      }                                                                        \
    }                                                                          \
    __builtin_amdgcn_s_setprio(0);                                             \
    _Pragma("unroll") for (int m = 0; m < 2; m++) {                            \
      float sum = 0.0f;                                                        \
      _Pragma("unroll") for (int n = 0; n < 4; n++) {                          \
        _Pragma("unroll") for (int j = 0; j < 4; j++) {                        \
          float p = fast_exp2(s[m][n][j]);                                     \
          s[m][n][j] = p;                                                      \
          sum += p;                                                            \
        }                                                                      \
        unsigned int u0 = bfbits(s[m][n][0]) | (bfbits(s[m][n][1]) << 16);     \
        unsigned int u1 = bfbits(s[m][n][2]) | (bfbits(s[m][n][3]) << 16);     \
        *reinterpret_cast<uint2*>(                                             \
            &Ps[wid][(m * 16 + l15) * 64 + ((n * 16 + l4 * 4) ^ swz)]) =       \
            make_uint2(u0, u1);                                                \
      }                                                                        \
      lst[m] += sum;                                                           \
    }                                                                          \
    __builtin_amdgcn_s_setprio(1);                                             \
    _Pragma("unroll") for (int ks = 0; ks < 2; ks++) {                         \
      _Pragma("unroll") for (int m = 0; m < 2; m++) {                          \
        bf16x8 pf = *reinterpret_cast<const bf16x8*>(                          \
            &Ps[wid][(m * 16 + l15) * 64 + ((ks * 32 + l4 * 8) ^ swz)]);       \
        _Pragma("unroll") for (int n = 0; n < 4; n++)                          \
          accO[m][n] = __builtin_amdgcn_mfma_f32_16x16x32_bf16(                \
              vf[ks][n], pf, accO[m][n], 0, 0, 0);                             \
      }                                                                        \
    }                                                                          \
    __builtin_amdgcn_s_setprio(0);                                             \
  }

#define LOADV(vf, kvs)                                                         \
  {                                                                            \
    _Pragma("unroll") for (int ks = 0; ks < 2; ks++)                           \
      _Pragma("unroll") for (int n = 0; n < 4; n++)                            \
        vf[ks][n] = *reinterpret_cast<const bf16x8*>(                          \
            vh + (size_t)(n * 16 + l15) * T + (kvs) + ks * 32 + l4 * 8);       \
  }

  STAGE128(0, kvbase);
  __syncthreads();
  int cur = 0;

  for (int r8 = 0; r8 < 8; r8++) {
    int kv0 = kvbase + r8 * 128;
    bf16x8 vf0[2][4];
    LOADV(vf0, kv0);                       // arrives during STAGE+QK0+SM0
    if (r8 + 1 < 8) STAGE128(cur ^ 1, kv0 + 128);
    bf16x8 vf1[2][4];
    LOADV(vf1, kv0 + 64);                  // flies under SUBTILE(0)
    SUBTILE(0, vf0);
    SUBTILE(1, vf1);
    __syncthreads();
    cur ^= 1;
  }
#undef SUBTILE
#undef LOADV
#undef STAGE128

  int b = bh >> 4, hh = bh & 15;
#pragma unroll
  for (int m = 0; m < 2; m++) {
    float l = lst[m];
    l += __shfl_xor(l, 16);
    l += __shfl_xor(l, 32);
    int row = q0 + m * 16 + l15;
    if (l4 == 0) lp[(size_t)bh * 2048 + row] = l;
#pragma unroll
    for (int n = 0; n < 4; n++) {
      ushort4 pk;                          // unnormalized partial O, bf16
      pk.x = (unsigned short)bfbits(accO[m][n][0]);
      pk.y = (unsigned short)bfbits(accO[m][n][1]);
      pk.z = (unsigned short)bfbits(accO[m][n][2]);
      pk.w = (unsigned short)bfbits(accO[m][n][3]);
      *reinterpret_cast<ushort4*>(
          &op[(size_t)(b * 2048 + row) * 1024 + hh * 64 + n * 16 + l4 * 4]) = pk;
    }
  }
}

// ---------------- Combine: attno = (Oa + Ob) / (la + lb) ----------------
__global__ __launch_bounds__(256)
void attn_combine(const unsigned short* __restrict__ opA,
                  const unsigned short* __restrict__ opB,
                  const float* __restrict__ lpA, const float* __restrict__ lpB,
                  unsigned short* __restrict__ attno) {
  int i0 = (blockIdx.x * 256 + threadIdx.x) * 8;   // 8 consecutive d within one head
  int r = i0 >> 10, c = i0 & 1023;
  int lidx = ((r >> 11) * 16 + (c >> 6)) * 2048 + (r & 2047);
  float inv = 1.0f / (lpA[lidx] + lpB[lidx]);
  bf16x8 a = *reinterpret_cast<const bf16x8*>(opA + i0);
  bf16x8 bb = *reinterpret_cast<const bf16x8*>(opB + i0);
  bf16x8 o;
#pragma unroll
  for (int k = 0; k < 8; k++)
    o[k] = (short)(unsigned short)bfbits(
        (bf2f((unsigned short)a[k]) + bf2f((unsigned short)bb[k])) * inv);
  *reinterpret_cast<bf16x8*>(attno + i0) = o;
}

extern "C" void kernel_launch(void* const* d_in, const int* in_sizes, int n_in,
                              void* d_out, int out_size, void* d_ws, size_t ws_size,
                              hipStream_t stream) {
  const float* x     = (const float*)d_in[0];
  const float* W_qkv = (const float*)d_in[1];
  const float* b_qkv = (const float*)d_in[2];
  const float* W_out = (const float*)d_in[3];
  const float* b_out = (const float*)d_in[4];
  const float* gamma = (const float*)d_in[5];
  const float* beta  = (const float*)d_in[6];
  float* out = (float*)d_out;

  char* ws = (char*)d_ws;
  const size_t MB = 1024 * 1024;
  unsigned short* h     = (unsigned short*)(ws);                 // [0,8) dead after QKV
  unsigned short* WqkvT = (unsigned short*)(ws + 8 * MB);        // [8,14) dead after QKV
  unsigned short* opA   = (unsigned short*)(ws);                 // [0,8)
  unsigned short* opB   = (unsigned short*)(ws + 8 * MB);        // [8,16)
  float*          lpA   = (float*)(ws + 16 * MB);                // 512 KB
  float*          lpB   = (float*)(ws + 16 * MB + 512 * 1024);   // 512 KB
  unsigned short* WoutT = (unsigned short*)(ws + 17 * MB);       // [17,19)
  unsigned short* qb    = (unsigned short*)(ws + 19 * MB);       // [19,27) dead after attn
  unsigned short* attno = (unsigned short*)(ws + 19 * MB);       // combine output
  unsigned short* kb    = (unsigned short*)(ws + 27 * MB);       // [27,35)
  unsigned short* vTb   = (unsigned short*)(ws + 35 * MB);       // [35,43)

  ln_kernel<<<4096, 256, 0, stream>>>(x, gamma, beta, h);
  transpose_cast_kernel<<<dim3(96, 32), 256, 0, stream>>>(W_qkv, WqkvT, 1024, 3072);
  transpose_cast_kernel<<<dim3(32, 32), 256, 0, stream>>>(W_out, WoutT, 1024, 1024);
  gemm128<128, 0><<<dim3(24, 32), 256, 0, stream>>>(h, WqkvT, 1024, b_qkv, qb, kb, vTb, nullptr, nullptr);
  attn_kernel<<<1024, 256, 0, stream>>>(qb, kb, vTb, opA, opB, lpA, lpB);
  attn_combine<<<2048, 256, 0, stream>>>(opA, opB, lpA, lpB, attno);
  gemm128<64, 1><<<dim3(8, 64), 256, 0, stream>>>(attno, WoutT, 1024, b_out, nullptr, nullptr, nullptr, x, out);
}